// Round 10
// baseline (509.085 us; speedup 1.0000x reference)
//
#include <hip/hip_runtime.h>
#include <hip/hip_fp16.h>
#include <math.h>

#define N 6000
#define FIN 300
#define HID 128
#define NH 8
#define ALPHA 0.2f
#define NBR_CAP 512
#define KSPLIT 8
#define TM 128
#define KC 64
#define NCH ((N + KC - 1) / KC)   // 94

typedef unsigned short u16;
typedef unsigned int u32;
typedef short bf16x8 __attribute__((ext_vector_type(8)));
typedef float f32x4 __attribute__((ext_vector_type(4)));

static __device__ __forceinline__ u16 f2bf(float f) {
    u32 u = __float_as_uint(f);
    u32 r = (u + 0x7fff + ((u >> 16) & 1)) >> 16;   // round-to-nearest-even
    return (u16)r;
}
static __device__ __forceinline__ u16 f2h(float f) {
    return __half_as_ushort(__float2half(f));
}

// K0: build neighbor lists, GLOBALLY ASCENDING in m (lane-major compaction).
// Required by gat1_mfma's moving-pointer scatter.
__global__ void build_nbr(const float* __restrict__ adj,
                          u16* __restrict__ nbr,
                          int* __restrict__ ncnt) {
    int n = blockIdx.x;
    int t = threadIdx.x;
    int lane = t & 63, w = t >> 6;
    __shared__ u16 lbuf[4][256];
    __shared__ int wc[4];
    const int seg = N / 4;                 // 1500 (multiple of 4)
    int start = w * seg, end = start + seg;
    const float* row = adj + (size_t)n * N;
    int cnt = 0;
    for (int base = start; base < end; base += 256) {
        int m0 = base + 4 * lane;
        float4 v = make_float4(0.f, 0.f, 0.f, 0.f);
        if (m0 < end) v = *(const float4*)(row + m0);
        bool p0 = v.x > 0.5f, p1 = v.y > 0.5f, p2 = v.z > 0.5f, p3 = v.w > 0.5f;
        unsigned long long mk0 = __ballot(p0);
        unsigned long long mk1 = __ballot(p1);
        unsigned long long mk2 = __ballot(p2);
        unsigned long long mk3 = __ballot(p3);
        unsigned long long below = (1ull << lane) - 1ull;
        int off = cnt + __popcll(mk0 & below) + __popcll(mk1 & below)
                      + __popcll(mk2 & below) + __popcll(mk3 & below);
        if (p0) { if (off < 256) lbuf[w][off] = (u16)(m0 + 0); off++; }
        if (p1) { if (off < 256) lbuf[w][off] = (u16)(m0 + 1); off++; }
        if (p2) { if (off < 256) lbuf[w][off] = (u16)(m0 + 2); off++; }
        if (p3) { if (off < 256) lbuf[w][off] = (u16)(m0 + 3); off++; }
        cnt += __popcll(mk0) + __popcll(mk1) + __popcll(mk2) + __popcll(mk3);
    }
    if (cnt > 256) cnt = 256;
    if (lane == 0) wc[w] = cnt;
    __syncthreads();
    int offset = 0;
    for (int i = 0; i < w; i++) offset += wc[i];
    for (int i = lane; i < cnt; i += 64) {
        int idx = offset + i;
        if (idx < NBR_CAP) nbr[(size_t)n * NBR_CAP + idx] = lbuf[w][i];
    }
    if (t == 0) {
        int total = wc[0] + wc[1] + wc[2] + wc[3];
        ncnt[n] = total < NBR_CAP ? total : NBR_CAP;
    }
}

// K1: x @ W_heads -> WhbT[h][c][m] (bf16, direct store from acc), fused f1/f2.
__global__ void gemm_wh(const float* __restrict__ x,
                        const float* __restrict__ W,
                        const float* __restrict__ a_heads,
                        u16* __restrict__ WhbT,
                        float* __restrict__ f1, float* __restrict__ f2) {
    int h = blockIdx.y;
    int n0 = blockIdx.x * 64;
    __shared__ float xs[64][21];
    __shared__ float bs[20][128];
    int t = threadIdx.x;
    int tx = t & 31, ty = t >> 5;
    float acc[8][4] = {};
    for (int k0 = 0; k0 < FIN; k0 += 20) {
        for (int i = t; i < 64 * 20; i += 256) {
            int r = i / 20, c = i - r * 20;
            int n = n0 + r;
            xs[r][c] = (n < N) ? x[(size_t)n * FIN + k0 + c] : 0.f;
        }
        for (int i = t; i < 20 * 128; i += 256) {
            int r = i >> 7, c = i & 127;
            bs[r][c] = W[((size_t)h * FIN + (k0 + r)) * HID + c];
        }
        __syncthreads();
#pragma unroll
        for (int kk = 0; kk < 20; kk++) {
            float b[4];
#pragma unroll
            for (int j = 0; j < 4; j++) b[j] = bs[kk][tx * 4 + j];
#pragma unroll
            for (int i = 0; i < 8; i++) {
                float a = xs[ty * 8 + i][kk];
#pragma unroll
                for (int j = 0; j < 4; j++) acc[i][j] += a * b[j];
            }
        }
        __syncthreads();
    }
    float a1c[4], a2c[4];
#pragma unroll
    for (int j = 0; j < 4; j++) {
        a1c[j] = a_heads[(size_t)h * 2 * HID + tx * 4 + j];
        a2c[j] = a_heads[(size_t)h * 2 * HID + HID + tx * 4 + j];
    }
    for (int i = 0; i < 8; i++) {
        int n = n0 + ty * 8 + i;
        float s1 = 0.f, s2 = 0.f;
#pragma unroll
        for (int j = 0; j < 4; j++) { s1 += acc[i][j] * a1c[j]; s2 += acc[i][j] * a2c[j]; }
        for (int d = 1; d <= 16; d <<= 1) { s1 += __shfl_xor(s1, d); s2 += __shfl_xor(s2, d); }
        if (n < N && tx == 0) { f1[h * N + n] = s1; f2[h * N + n] = s2; }
    }
    bool fast = (n0 + 64 <= N);
#pragma unroll
    for (int j = 0; j < 4; j++) {
        int c = tx * 4 + j;
        u16* dst = WhbT + ((size_t)h * HID + c) * N + n0 + ty * 8;
        if (fast) {
            u32 w0 = (u32)f2bf(acc[0][j]) | ((u32)f2bf(acc[1][j]) << 16);
            u32 w1 = (u32)f2bf(acc[2][j]) | ((u32)f2bf(acc[3][j]) << 16);
            u32 w2 = (u32)f2bf(acc[4][j]) | ((u32)f2bf(acc[5][j]) << 16);
            u32 w3 = (u32)f2bf(acc[6][j]) | ((u32)f2bf(acc[7][j]) << 16);
            *(uint4*)dst = make_uint4(w0, w1, w2, w3);
        } else {
            for (int i = 0; i < 8; i++)
                if (n0 + ty * 8 + i < N) dst[i] = f2bf(acc[i][j]);
        }
    }
}

// K3: layer-1 masked-softmax + PV via MFMA 16x16x32 (m92-verified pattern).
__global__ __launch_bounds__(256)
void gat1_mfma(const u16* __restrict__ WhbT,
               const float* __restrict__ f1, const float* __restrict__ f2,
               const u16* __restrict__ nbr, const int* __restrict__ ncnt,
               float* __restrict__ hcat) {
    int tile = blockIdx.x, h = blockIdx.y;
    int n0 = tile * TM;
    int t = threadIdx.x;
    int lane = t & 63, wid = t >> 6;
    int l4 = lane >> 4;            // 0..3
    int lr = lane & 15;            // 0..15

    __shared__ u16 Pl[TM][KC + 8];   // row stride 144 B
    __shared__ u16 Bt[HID][KC + 8];
    __shared__ float swl[TM];

    int cnt = 0;
    const u16* lst = nullptr;
    float f1c = 0.f;
    if (t < TM) {
        int nrow = n0 + t;
        if (nrow < N) {
            cnt = ncnt[nrow];
            lst = nbr + (size_t)nrow * NBR_CAP;
            f1c = f1[h * N + nrow];
        }
    }
    int p = 0;
    float sw = 0.f;
    const float* f2p = f2 + (size_t)h * N;
    const u16* wsrc = WhbT + (size_t)h * HID * N;

    f32x4 acc[2][8];
#pragma unroll
    for (int rt = 0; rt < 2; rt++)
#pragma unroll
        for (int ct = 0; ct < 8; ct++)
            acc[rt][ct] = (f32x4){0.f, 0.f, 0.f, 0.f};

    for (int ch = 0; ch < NCH; ch++) {
        int m0 = ch * KC, mend = m0 + KC;
        // stage B chunk (all 256 threads; 32 u16 each)
        {
            int c = t >> 1, seg = t & 1;
            int mb = m0 + seg * 32;
            const u16* src = wsrc + (size_t)c * N + mb;
            if (mb + 32 <= N) {
                uint4 v0 = ((const uint4*)src)[0];
                uint4 v1 = ((const uint4*)src)[1];
                uint4 v2 = ((const uint4*)src)[2];
                uint4 v3 = ((const uint4*)src)[3];
                *(uint4*)&Bt[c][seg * 32 + 0]  = v0;
                *(uint4*)&Bt[c][seg * 32 + 8]  = v1;
                *(uint4*)&Bt[c][seg * 32 + 16] = v2;
                *(uint4*)&Bt[c][seg * 32 + 24] = v3;
            } else {
                for (int j = 0; j < 32; j++)
                    Bt[c][seg * 32 + j] = (mb + j < N) ? src[j] : (u16)0;
            }
        }
        // zero + scatter P strip (threads < 128; sorted list, moving ptr)
        if (t < TM) {
#pragma unroll
            for (int j = 0; j < 8; j++)
                *(uint4*)&Pl[t][8 * j] = make_uint4(0u, 0u, 0u, 0u);
            while (p < cnt) {
                int mloc[8];
                float zv[8];
                int k = 0;
#pragma unroll
                for (int j = 0; j < 8; j++) {
                    int idx = p + j;
                    mloc[j] = (idx < cnt) ? (int)lst[idx] : 0x7fffffff;
                }
#pragma unroll
                for (int j = 0; j < 8; j++) {
                    bool ok = mloc[j] < mend;
                    zv[j] = ok ? f2p[mloc[j]] : 0.f;
                    k += ok ? 1 : 0;
                }
#pragma unroll
                for (int j = 0; j < 8; j++) {
                    if (mloc[j] < mend) {
                        float z = f1c + zv[j];
                        z = (z >= 0.f) ? z : ALPHA * z;
                        u16 bw = f2bf(__expf(z));
                        Pl[t][mloc[j] - m0] = bw;
                        sw += __uint_as_float((u32)bw << 16);
                    }
                }
                p += k;
                if (k < 8) break;
            }
        }
        __syncthreads();
        // MFMA: contiguous-8 fragments (m92 pattern)
#pragma unroll
        for (int ks = 0; ks < 2; ks++) {
            int kb = ks * 32 + 8 * l4;
            bf16x8 a0 = *(const bf16x8*)&Pl[32 * wid + lr][kb];
            bf16x8 a1 = *(const bf16x8*)&Pl[32 * wid + 16 + lr][kb];
#pragma unroll
            for (int ct = 0; ct < 8; ct++) {
                bf16x8 b = *(const bf16x8*)&Bt[16 * ct + lr][kb];
                acc[0][ct] = __builtin_amdgcn_mfma_f32_16x16x32_bf16(a0, b, acc[0][ct], 0, 0, 0);
                acc[1][ct] = __builtin_amdgcn_mfma_f32_16x16x32_bf16(a1, b, acc[1][ct], 0, 0, 0);
            }
        }
        __syncthreads();
    }
    if (t < TM) swl[t] = sw;
    __syncthreads();
    // epilogue: C/D (m89-verified): col = lane&15, row = 4*(lane>>4) + reg
#pragma unroll
    for (int rt = 0; rt < 2; rt++) {
#pragma unroll
        for (int reg = 0; reg < 4; reg++) {
            int rl = 32 * wid + 16 * rt + 4 * l4 + reg;
            int n = n0 + rl;
            if (n < N) {
                float inv = 1.f / swl[rl];
                float* orow = hcat + (size_t)n * (NH * HID) + h * HID;
#pragma unroll
                for (int ct = 0; ct < 8; ct++) {
                    float v = acc[rt][ct][reg] * inv;
                    v = (v > 0.f) ? v : expm1f(v);
                    orow[16 * ct + lr] = v;
                }
            }
        }
    }
}

// K4: partial = hcat(6000x1024) @ W_out(1024x128), split-K over 8 slices.
__global__ void gemm_out(const float* __restrict__ hcat,
                         const float* __restrict__ W_out,
                         float* __restrict__ partial) {
    int n0 = blockIdx.x * 64;
    int ks = blockIdx.y;
    __shared__ float xs[64][17];
    __shared__ float bs[16][128];
    int t = threadIdx.x;
    int tx = t & 31, ty = t >> 5;
    float acc[8][4] = {};
    int kbeg = ks * 128, kend = kbeg + 128;
    for (int k0 = kbeg; k0 < kend; k0 += 16) {
        for (int i = t; i < 64 * 16; i += 256) {
            int r = i >> 4, c = i & 15;
            int n = n0 + r;
            xs[r][c] = (n < N) ? hcat[(size_t)n * 1024 + k0 + c] : 0.f;
        }
        for (int i = t; i < 16 * 128; i += 256) {
            int r = i >> 7, c = i & 127;
            bs[r][c] = W_out[(size_t)(k0 + r) * HID + c];
        }
        __syncthreads();
#pragma unroll
        for (int kk = 0; kk < 16; kk++) {
            float b[4];
#pragma unroll
            for (int j = 0; j < 4; j++) b[j] = bs[kk][tx * 4 + j];
#pragma unroll
            for (int i = 0; i < 8; i++) {
                float a = xs[ty * 8 + i][kk];
#pragma unroll
                for (int j = 0; j < 4; j++) acc[i][j] += a * b[j];
            }
        }
        __syncthreads();
    }
    float* pout = partial + (size_t)ks * N * HID;
    for (int i = 0; i < 8; i++) {
        int n = n0 + ty * 8 + i;
        if (n < N) {
#pragma unroll
            for (int j = 0; j < 4; j++)
                pout[(size_t)n * HID + tx * 4 + j] = acc[i][j];
        }
    }
}

// K4b: sum the 8 K-split partials -> fp16 Wh2h shadow; fused g1/g2.
__global__ void reduce_wh2(const float* __restrict__ partial,
                           const float* __restrict__ a_out,
                           u16* __restrict__ Wh2h,
                           float* __restrict__ g1, float* __restrict__ g2) {
    int idx = blockIdx.x * 256 + threadIdx.x;      // float4 index
    float4 v = *(const float4*)(partial + 4 * (size_t)idx);
#pragma unroll
    for (int s = 1; s < KSPLIT; s++) {
        const float4 q = *(const float4*)(partial + (size_t)s * N * HID + 4 * (size_t)idx);
        v.x += q.x; v.y += q.y; v.z += q.z; v.w += q.w;
    }
    ushort4 h4;
    h4.x = f2h(v.x); h4.y = f2h(v.y); h4.z = f2h(v.z); h4.w = f2h(v.w);
    *(ushort4*)(Wh2h + 4 * (size_t)idx) = h4;

    int row = idx >> 5, cg = idx & 31;
    float p1 = v.x * a_out[4 * cg] + v.y * a_out[4 * cg + 1]
             + v.z * a_out[4 * cg + 2] + v.w * a_out[4 * cg + 3];
    float p2 = v.x * a_out[HID + 4 * cg] + v.y * a_out[HID + 4 * cg + 1]
             + v.z * a_out[HID + 4 * cg + 2] + v.w * a_out[HID + 4 * cg + 3];
    for (int d = 1; d <= 16; d <<= 1) { p1 += __shfl_xor(p1, d); p2 += __shfl_xor(p2, d); }
    if ((threadIdx.x & 31) == 0) { g1[row] = p1; g2[row] = p2; }
}

// K6: layer-2 fused masked-softmax + PV, fp16 gather.
__global__ void gat2(const u16* __restrict__ Wh2h,
                     const float* __restrict__ g1, const float* __restrict__ g2,
                     const u16* __restrict__ nbr,
                     const int* __restrict__ ncnt,
                     float* __restrict__ out) {
    int n = blockIdx.x, t = threadIdx.x;
    int s = t >> 4, op = t & 15;
    int cnt = ncnt[n];
    const u16* lst = nbr + (size_t)n * NBR_CAP;
    __shared__ float2 wm[NBR_CAP];
    __shared__ float accl[16][16][9];
    __shared__ float swl[16];

    float g1c = g1[n];
    for (int i = t; i < cnt; i += 256) {
        int m = lst[i];
        float z = g1c + g2[m];
        z = (z >= 0.f) ? z : ALPHA * z;
        wm[i] = make_float2(__expf(z), __uint_as_float((u32)m << 8));
    }
    __syncthreads();

    const char* base = (const char*)Wh2h + (op << 4);
    float acc[8] = {};
    float sw = 0.f;
    int j = s;
    for (; j + 16 < cnt; j += 32) {
        float2 p0 = wm[j];
        float2 p1 = wm[j + 16];
        const uint4 va = *(const uint4*)(base + __float_as_uint(p0.y));
        const uint4 vb = *(const uint4*)(base + __float_as_uint(p1.y));
        float w0 = p0.x, w1 = p1.x;
        acc[0] += w0 * __half2float(__ushort_as_half((u16)(va.x & 0xffff)));
        acc[1] += w0 * __half2float(__ushort_as_half((u16)(va.x >> 16)));
        acc[2] += w0 * __half2float(__ushort_as_half((u16)(va.y & 0xffff)));
        acc[3] += w0 * __half2float(__ushort_as_half((u16)(va.y >> 16)));
        acc[4] += w0 * __half2float(__ushort_as_half((u16)(va.z & 0xffff)));
        acc[5] += w0 * __half2float(__ushort_as_half((u16)(va.z >> 16)));
        acc[6] += w0 * __half2float(__ushort_as_half((u16)(va.w & 0xffff)));
        acc[7] += w0 * __half2float(__ushort_as_half((u16)(va.w >> 16)));
        acc[0] += w1 * __half2float(__ushort_as_half((u16)(vb.x & 0xffff)));
        acc[1] += w1 * __half2float(__ushort_as_half((u16)(vb.x >> 16)));
        acc[2] += w1 * __half2float(__ushort_as_half((u16)(vb.y & 0xffff)));
        acc[3] += w1 * __half2float(__ushort_as_half((u16)(vb.y >> 16)));
        acc[4] += w1 * __half2float(__ushort_as_half((u16)(vb.z & 0xffff)));
        acc[5] += w1 * __half2float(__ushort_as_half((u16)(vb.z >> 16)));
        acc[6] += w1 * __half2float(__ushort_as_half((u16)(vb.w & 0xffff)));
        acc[7] += w1 * __half2float(__ushort_as_half((u16)(vb.w >> 16)));
        sw += w0 + w1;
    }
    if (j < cnt) {
        float2 p0 = wm[j];
        const uint4 va = *(const uint4*)(base + __float_as_uint(p0.y));
        float w0 = p0.x;
        acc[0] += w0 * __half2float(__ushort_as_half((u16)(va.x & 0xffff)));
        acc[1] += w0 * __half2float(__ushort_as_half((u16)(va.x >> 16)));
        acc[2] += w0 * __half2float(__ushort_as_half((u16)(va.y & 0xffff)));
        acc[3] += w0 * __half2float(__ushort_as_half((u16)(va.y >> 16)));
        acc[4] += w0 * __half2float(__ushort_as_half((u16)(va.z & 0xffff)));
        acc[5] += w0 * __half2float(__ushort_as_half((u16)(va.z >> 16)));
        acc[6] += w0 * __half2float(__ushort_as_half((u16)(va.w & 0xffff)));
        acc[7] += w0 * __half2float(__ushort_as_half((u16)(va.w >> 16)));
        sw += w0;
    }
#pragma unroll
    for (int c = 0; c < 8; c++) accl[s][op][c] = acc[c];
    if (op == 0) swl[s] = sw;
    __syncthreads();

    if (t < 128) {
        int c = t;
        float r = 0.f;
#pragma unroll
        for (int k = 0; k < 16; k++) r += accl[k][c >> 3][c & 7];
        float swt = 0.f;
#pragma unroll
        for (int k = 0; k < 16; k++) swt += swl[k];
        out[(size_t)n * HID + c] = r / swt;
    }
}

extern "C" void kernel_launch(void* const* d_in, const int* in_sizes, int n_in,
                              void* d_out, int out_size, void* d_ws, size_t ws_size,
                              hipStream_t stream) {
    const float* x       = (const float*)d_in[0];
    const float* adj     = (const float*)d_in[1];
    const float* W_heads = (const float*)d_in[2];
    const float* a_heads = (const float*)d_in[3];
    const float* W_out   = (const float*)d_in[4];
    const float* a_out   = (const float*)d_in[5];
    float* out = (float*)d_out;

    char* wsb = (char*)d_ws;
    size_t off = 0;
    auto alloc = [&](size_t bytes) {
        void* p = wsb + off;
        off += (bytes + 255) & ~(size_t)255;
        return p;
    };
    float* partial = (float*)alloc(sizeof(float) * (size_t)KSPLIT * N * HID); // 24.576 MB
    u16*   WhbT = (u16*)  alloc(sizeof(u16)   * (size_t)NH * HID * N);        // 12.288 MB
    float* hcat = (float*)alloc(sizeof(float) * (size_t)N * NH * HID);
    u16*   Wh2h = (u16*)  alloc(sizeof(u16)   * (size_t)N * HID);
    float* f1   = (float*)alloc(sizeof(float) * (size_t)NH * N);
    float* f2   = (float*)alloc(sizeof(float) * (size_t)NH * N);
    float* g1   = (float*)alloc(sizeof(float) * (size_t)N);
    float* g2   = (float*)alloc(sizeof(float) * (size_t)N);
    u16* nbr    = (u16*)  alloc(sizeof(u16)   * (size_t)N * NBR_CAP);
    int* ncnt   = (int*)  alloc(sizeof(int)   * (size_t)N);

    hipLaunchKernelGGL(build_nbr, dim3(N), dim3(256), 0, stream, adj, nbr, ncnt);
    hipLaunchKernelGGL(gemm_wh, dim3((N + 63) / 64, NH), dim3(256), 0, stream,
                       x, W_heads, a_heads, WhbT, f1, f2);
    hipLaunchKernelGGL(gat1_mfma, dim3((N + TM - 1) / TM, NH), dim3(256), 0, stream,
                       WhbT, f1, f2, nbr, ncnt, hcat);
    hipLaunchKernelGGL(gemm_out, dim3((N + 63) / 64, KSPLIT), dim3(256), 0, stream,
                       hcat, W_out, partial);
    hipLaunchKernelGGL(reduce_wh2, dim3(N * HID / 4 / 256), dim3(256), 0, stream,
                       partial, a_out, Wh2h, g1, g2);
    hipLaunchKernelGGL(gat2, dim3(N), dim3(256), 0, stream, Wh2h, g1, g2, nbr, ncnt, out);
}